// Round 3
// baseline (189.732 us; speedup 1.0000x reference)
//
#include <hip/hip_runtime.h>
#include <cstdint>
#include <cstddef>

typedef unsigned int u32;
typedef unsigned long long u64;

#define NTOT 122740      // total proposals per batch
#define NQ   30685       // NTOT/4 uint4 per batch
#define NPAIR 61370      // NTOT/2 proposal pairs per batch
#define KTOP 1024        // top-K kept per batch (deterministic bin-cutoff set)
#define WIN  256         // IoU-matrix window over the sorted list
#define NBIN 4096
#define SCORE_T 0.25f
#define TBITS 0x3E800000u   // bit pattern of 0.25f
#define CSTRIDE 64          // counter padding (u32s) -> 256 B apart

// level layout: [offset, count) per pyramid level (batch strides in floats: N*6)
// L2: [0,      92416)  152x152 s4   N=92416
// L3: [92416,  115520) 76x76   s8   N=23104
// L4: [115520, 121296) 38x38   s16  N=5776
// L5: [121296, 122740) 19x19   s32  N=1444

// ws layout (bytes):
//   hist/binpos: 32*4096*4 = 524288   @ 0        (hist, then in-place bin cursors)
//   counters:    32*64*4   = 8192     @ 524288   ([0]=n, [1]=B per batch)
//   compact:     32*1024*8 = 262144   @ 532480
//   scores:      32*NTOT*4 = 15710720 @ 794624
#define WS_COUNTERS 524288
#define WS_COMPACT  532480
#define WS_SCORES   794624

// ---------------------------------------------------------------- helpers
__device__ __forceinline__ float sigm(float x) { return 1.0f / (1.0f + expf(-x)); }

// valid scores [0.25,1) -> bins 1..4095 (monotone in bits); 0 = invalid
__device__ __forceinline__ int score_bin(u32 bits) {
  return min(4095, 1 + (int)((bits - TBITS) >> 12));
}

__device__ __forceinline__ u64 shfl_u64(u64 x, int src) {
  int lo = __shfl((int)(u32)x, src, 64);
  int hi = __shfl((int)(u32)(x >> 32), src, 64);
  return ((u64)(u32)hi << 32) | (u32)lo;
}

__device__ float4 decode_box_from_gidx(u32 gidx, int b,
    const float* __restrict__ p2, const float* __restrict__ p3,
    const float* __restrict__ p4, const float* __restrict__ p5)
{
  const float* p; int t, H, W; float stride;
  float aw0, ah0, aw1, ah1, aw2, ah2, aw3, ah3;
  if (gidx < 92416u) {
    p = p2 + (size_t)b * 92416 * 6; t = (int)gidx; H = 152; W = 152; stride = 4.0f;
    aw0=12.f; ah0=16.f; aw1=19.f; ah1=36.f; aw2=40.f; ah2=28.f; aw3=36.f; ah3=75.f;
  } else if (gidx < 115520u) {
    p = p3 + (size_t)b * 23104 * 6; t = (int)(gidx - 92416u); H = 76; W = 76; stride = 8.0f;
    aw0=36.f; ah0=75.f; aw1=76.f; ah1=55.f; aw2=72.f; ah2=146.f; aw3=142.f; ah3=110.f;
  } else if (gidx < 121296u) {
    p = p4 + (size_t)b * 5776 * 6; t = (int)(gidx - 115520u); H = 38; W = 38; stride = 16.0f;
    aw0=72.f; ah0=146.f; aw1=142.f; ah1=110.f; aw2=192.f; ah2=243.f; aw3=459.f; ah3=401.f;
  } else {
    p = p5 + (size_t)b * 1444 * 6; t = (int)(gidx - 121296u); H = 19; W = 19; stride = 32.0f;
    aw0=142.f; ah0=110.f; aw1=192.f; ah1=243.f; aw2=300.f; ah2=300.f; aw3=459.f; ah3=401.f;
  }
  int HW = H * W;
  int a = t / HW;
  int r = t - a * HW;
  int y = r / W;
  int x = r - y * W;
  const float* q = p + (size_t)t * 6;
  float2 t01 = *(const float2*)(q + 0);
  float2 t23 = *(const float2*)(q + 2);
  float cx = (sigm(t01.x) + (float)x) * stride;
  float cy = (sigm(t01.y) + (float)y) * stride;
  float aw = (a == 0) ? aw0 : (a == 1) ? aw1 : (a == 2) ? aw2 : aw3;
  float ah = (a == 0) ? ah0 : (a == 1) ? ah1 : (a == 2) ? ah2 : ah3;
  float bw = expf(t23.x) * aw;
  float bh = expf(t23.y) * ah;
  return make_float4(cx - 0.5f * bw, cy - 0.5f * bh, cx + 0.5f * bw, cy + 0.5f * bh);
}

__device__ __forceinline__ bool iou_gt(float4 A, float4 B) {
  float ltx = fmaxf(A.x, B.x), lty = fmaxf(A.y, B.y);
  float rbx = fminf(A.z, B.z), rby = fminf(A.w, B.w);
  float w = fmaxf(rbx - ltx, 0.0f), h = fmaxf(rby - lty, 0.0f);
  float inter = w * h;
  float a1 = fmaxf(A.z - A.x, 0.0f) * fmaxf(A.w - A.y, 0.0f);
  float a2 = fmaxf(B.z - B.x, 0.0f) * fmaxf(B.w - B.y, 0.0f);
  float iou = inter / (a1 + a2 - inter + 1e-9f);
  return iou > 0.5f;
}

// ---------------------------------------------------------------- Z: zero hist+counters
__global__ __launch_bounds__(1024)
void zero_kernel(u32* w) {
  int t = blockIdx.x * 1024 + threadIdx.x;   // 130*1024 = 133120 u32 = hist+counters
  if (t < 133120) w[t] = 0u;
}

// ---------------------------------------------------------------- A: decode scores + hist
__global__ __launch_bounds__(256)
void decode_score_hist(const float* __restrict__ p2, const float* __restrict__ p3,
                       const float* __restrict__ p4, const float* __restrict__ p5,
                       u32* __restrict__ scores, u32* __restrict__ hist)
{
  __shared__ u32 lhist[NBIN];
  const int tid = threadIdx.x;
  const int b = blockIdx.y;
  for (int i = tid; i < NBIN; i += 256) lhist[i] = 0u;
  __syncthreads();

  uint2* srow = (uint2*)(scores + (size_t)b * NTOT);
  const int pbase = blockIdx.x * 2048;
  #pragma unroll 2
  for (int k = 0; k < 8; ++k) {
    int P = pbase + k * 256 + tid;
    if (P < NPAIR) {
      int t0 = 2 * P;
      const float* p; int l0, LN;
      if (t0 < 92416)       { p = p2; l0 = t0;          LN = 92416; }
      else if (t0 < 115520) { p = p3; l0 = t0 - 92416;  LN = 23104; }
      else if (t0 < 121296) { p = p4; l0 = t0 - 115520; LN = 5776;  }
      else                  { p = p5; l0 = t0 - 121296; LN = 1444;  }
      const float* q = p + ((size_t)b * LN + (size_t)l0) * 6 + 4;
      float4 v1 = *(const float4*)(q);      // conf0, cls0, t0_1, t1_1
      float4 v2 = *(const float4*)(q + 4);  // t2_1, t3_1, conf1, cls1
      float s0 = sigm(v1.x) * sigm(v1.y);
      float s1 = sigm(v2.z) * sigm(v2.w);
      u32 b0 = (s0 >= SCORE_T) ? __float_as_uint(s0) : 0u;
      u32 b1 = (s1 >= SCORE_T) ? __float_as_uint(s1) : 0u;
      srow[P] = make_uint2(b0, b1);
      if (b0) atomicAdd(&lhist[score_bin(b0)], 1u);
      if (b1) atomicAdd(&lhist[score_bin(b1)], 1u);
    }
  }
  __syncthreads();
  u32* gh = hist + (size_t)b * NBIN;
  for (int i = tid; i < NBIN; i += 256) {
    u32 v = lhist[i];
    if (v) atomicAdd(&gh[i], v);
  }
}

// ---------------------------------------------------------------- S: suffix-scan hist -> bin cursors
// One block per batch. Computes cutoff B (min bin with cnt_ge <= KTOP), n = cnt_ge(B),
// and rewrites hist[bin] := cnt_ge(bin+1) in place (= starting output cursor per bin,
// descending-score counting-sort placement).
__global__ __launch_bounds__(256)
void scan_kernel(u32* __restrict__ hist, u32* __restrict__ counters)
{
  __shared__ u32 shist[NBIN];
  __shared__ u32 scan[256];
  __shared__ int s_B, s_n;
  const int tid = threadIdx.x;
  const int b = blockIdx.x;
  u32* gh = hist + (size_t)b * NBIN;
  for (int i = tid; i < NBIN; i += 256) shist[i] = gh[i];
  __syncthreads();

  u32 loc[16];
  u32 g = 0;
  const int base = tid * 16;
  #pragma unroll
  for (int k = 0; k < 16; ++k) { loc[k] = shist[base + k]; g += loc[k]; }
  scan[tid] = g;
  __syncthreads();
  for (int off = 1; off < 256; off <<= 1) {
    u32 v = (tid + off < 256) ? scan[tid + off] : 0u;
    __syncthreads();
    scan[tid] += v;
    __syncthreads();
  }
  // scan[t] = cnt_ge(16t)
  if (tid == 0 && scan[0] <= (u32)KTOP) { s_B = 1; s_n = (int)scan[0]; }
  {
    u32 nxt = (tid < 255) ? scan[tid + 1] : 0u;
    if (scan[tid] > (u32)KTOP && nxt <= (u32)KTOP) {
      u32 c = nxt; int Bv = base + 16; u32 nv = nxt;
      for (int k = 15; k >= 0; --k) {
        c += loc[k];
        if (c <= (u32)KTOP) { Bv = base + k; nv = c; } else break;
      }
      s_B = Bv; s_n = (int)nv;
    }
  }
  // binpos[bin] = cnt_ge(bin+1), written in place over hist
  {
    u32 s = (tid < 255) ? scan[tid + 1] : 0u;
    for (int k = 15; k >= 0; --k) { gh[base + k] = s; s += loc[k]; }
  }
  __syncthreads();
  if (tid == 0) {
    counters[(size_t)b * CSTRIDE]     = (u32)s_n;
    counters[(size_t)b * CSTRIDE + 1] = (u32)max(s_B, 1);
  }
}

// ---------------------------------------------------------------- B1: filter + counting-sort scatter
// Survivors (bin >= B) are written DIRECTLY to their near-sorted slot:
// slot = cnt_gt(bin) + within-bin rank (atomic). List is sorted across bins,
// unordered only within a bin.
__global__ __launch_bounds__(256)
void filter_kernel(const u32* __restrict__ scores, u32* __restrict__ binpos,
                   const u32* __restrict__ counters, uint2* __restrict__ compact)
{
  const int tid = threadIdx.x;
  const int b = blockIdx.y;
  const int B = (int)counters[(size_t)b * CSTRIDE + 1];
  u32* bp = binpos + (size_t)b * NBIN;
  uint2* crow = compact + (size_t)b * KTOP;
  const uint4* sp = (const uint4*)(scores + (size_t)b * NTOT);
  const int i0 = blockIdx.x * 2048;
  const int i1 = min(i0 + 2048, NQ);
  for (int i = i0 + tid; i < i1; i += 256) {
    uint4 v = sp[i];
    u32 c4[4] = { v.x, v.y, v.z, v.w };
    #pragma unroll
    for (int c = 0; c < 4; ++c) {
      u32 bits = c4[c];
      if (bits) {
        int bin = score_bin(bits);
        if (bin >= B) {
          u32 slot = atomicAdd(&bp[bin], 1u);   // slot < n <= KTOP by construction
          if (slot < (u32)KTOP)                 // defensive
            crow[slot] = make_uint2(bits, (u32)(4 * i + c));
        }
      }
    }
  }
}

// ---------------------------------------------------------------- B2: finish sort + NMS
__global__ __launch_bounds__(1024, 1)
void sort_nms_kernel(const uint2* __restrict__ compact, const u32* __restrict__ counters,
                     const float* __restrict__ p2, const float* __restrict__ p3,
                     const float* __restrict__ p4, const float* __restrict__ p5,
                     float* __restrict__ out)
{
  const int b = blockIdx.x;
  const int tid = threadIdx.x;

  __shared__ u64 skey[KTOP];        // 8 KB, descending keys
  __shared__ float4 sbox[WIN];      // 4 KB
  __shared__ u64 smat[WIN * 4];     // 8 KB, [word][row]: smat[w*256+row]
  __shared__ float4 selbox[100];    // 1.6 KB
  __shared__ int s_misc[4];         // [2]=n_sel, [3]=need slow
  __shared__ int s_flag;

  const int n = min((int)counters[(size_t)b * CSTRIDE], KTOP);
  const uint2* crow = compact + (size_t)b * KTOP;

  // key: score desc major, idx asc minor (via ~gidx); sentinel 0 sorts last
  if (tid < n) {
    uint2 pr = crow[tid];
    skey[tid] = ((u64)pr.x << 32) | (u32)(~pr.y);
  } else {
    skey[tid] = 0ull;
  }
  __syncthreads();

  // list is sorted across bins; only within-bin disorder remains (few items/bin).
  // odd-even transposition with early exit: exact full sort.
  // HARD CAP 600 rounds (odd-even provably sorts 1024 elems in <=512 rounds)
  // so no code path can hang the device.
  for (int round = 0; round < 600; ++round) {
    if (tid == 0) s_flag = 0;
    __syncthreads();
    if (tid < 512) {                      // even pairs (2t, 2t+1)
      int p = 2 * tid;
      u64 a = skey[p], c = skey[p + 1];
      if (a < c) { skey[p] = c; skey[p + 1] = a; s_flag = 1; }
    }
    __syncthreads();
    if (tid < 511) {                      // odd pairs (2t+1, 2t+2)
      int p = 2 * tid + 1;
      u64 a = skey[p], c = skey[p + 1];
      if (a < c) { skey[p] = c; skey[p + 1] = a; s_flag = 1; }
    }
    __syncthreads();
    int f = s_flag;
    __syncthreads();
    if (!f) break;
  }

  const int Wn = min(n, WIN);

  // decode boxes for the window
  if (tid < WIN) {
    sbox[tid] = (tid < Wn) ? decode_box_from_gidx(~(u32)skey[tid], b, p2, p3, p4, p5)
                           : make_float4(0.f, 0.f, 0.f, 0.f);
  }
  __syncthreads();

  // IoU bitmask matrix. row = tid&255 (lane-consecutive), word = tid>>8 (wave-uniform)
  // -> inner sbox read is a wave-uniform broadcast: conflict-free.
  {
    int row = tid & 255, word = tid >> 8;
    u64 bits = 0;
    if (row < Wn) {
      float4 A = sbox[row];
      int j0 = word * 64;
      int je = min(64, Wn - j0);
      for (int j = 0; j < je; ++j)
        if (iou_gt(A, sbox[j0 + j])) bits |= (1ull << j);
    }
    smat[word * 256 + row] = bits;
  }
  __syncthreads();

  // greedy selection on wave 0: matrix rows distributed into registers
  // (lane l holds rows l, 64+l, 128+l, 192+l); row fetch via shfl (~40cy)
  // instead of LDS reads (~120cy) on the serial critical chain.
  if (tid < 64) {
    const int lane = tid;
    u64 m0[4], m1[4], m2[4], m3[4];
    #pragma unroll
    for (int w = 0; w < 4; ++w) {
      m0[w] = smat[w * 256 +   0 + lane];
      m1[w] = smat[w * 256 +  64 + lane];
      m2[w] = smat[w * 256 + 128 + lane];
      m3[w] = smat[w * 256 + 192 + lane];
    }
    u64 live[4];
    #pragma unroll
    for (int g2 = 0; g2 < 4; ++g2) {
      int lo = g2 * 64;
      live[g2] = (Wn >= lo + 64) ? ~0ull : (Wn > lo ? ((1ull << (Wn - lo)) - 1ull) : 0ull);
    }
    int sel = 0;
    #pragma unroll 1
    for (int w2 = 0; w2 < 4; ++w2) {
      while (live[w2] && sel < 100) {
        int j = (int)__ffsll(live[w2]) - 1;
        int p = (w2 << 6) + j;
        u64 r0, r1, r2, r3;
        if (w2 == 0)      { r0 = shfl_u64(m0[0], j); r1 = shfl_u64(m0[1], j); r2 = shfl_u64(m0[2], j); r3 = shfl_u64(m0[3], j); }
        else if (w2 == 1) { r0 = shfl_u64(m1[0], j); r1 = shfl_u64(m1[1], j); r2 = shfl_u64(m1[2], j); r3 = shfl_u64(m1[3], j); }
        else if (w2 == 2) { r0 = shfl_u64(m2[0], j); r1 = shfl_u64(m2[1], j); r2 = shfl_u64(m2[2], j); r3 = shfl_u64(m2[3], j); }
        else              { r0 = shfl_u64(m3[0], j); r1 = shfl_u64(m3[1], j); r2 = shfl_u64(m3[2], j); r3 = shfl_u64(m3[3], j); }
        live[0] &= ~r0; live[1] &= ~r1; live[2] &= ~r2; live[3] &= ~r3;
        live[w2] &= ~(1ull << j);     // self-bit (IoU(self)=1 sets it anyway)
        if (lane == 0) {
          float4 box = sbox[p];
          u64 k = skey[p];
          float sc = __uint_as_float((u32)(k >> 32));
          selbox[sel] = box;
          float* orow = out + (size_t)b * 500 + (size_t)sel * 5;
          orow[0] = box.x; orow[1] = box.y; orow[2] = box.z; orow[3] = box.w; orow[4] = sc;
        }
        sel++;
      }
    }
    if (lane == 0) {
      s_misc[2] = sel;
      s_misc[3] = (sel < 100 && n > WIN) ? 1 : 0;
    }
  }
  __syncthreads();

  // exact slow path beyond the window (statistically never taken)
  if (s_misc[3]) {
    if (tid < 64) {
      const int lane = tid;
      int sel = s_misc[2];
      for (int p = WIN; p < n && sel < 100; ++p) {
        u64 k = skey[p];
        float4 box = decode_box_from_gidx(~(u32)k, b, p2, p3, p4, p5);
        bool hit = false;
        if (lane < sel) hit = iou_gt(selbox[lane], box);
        if (lane + 64 < sel) hit = hit || iou_gt(selbox[lane + 64], box);
        u64 anyhit = __ballot(hit);
        if (anyhit == 0ull) {
          if (lane == 0) {
            selbox[sel] = box;
            float sc = __uint_as_float((u32)(k >> 32));
            float* orow = out + (size_t)b * 500 + (size_t)sel * 5;
            orow[0] = box.x; orow[1] = box.y; orow[2] = box.z; orow[3] = box.w; orow[4] = sc;
          }
          sel++;
        }
      }
      if (lane == 0) s_misc[2] = sel;
    }
  }
  __syncthreads();

  // zero-fill remaining rows
  const int nsel = s_misc[2];
  for (int i = tid; i < (100 - nsel) * 5; i += 1024)
    out[(size_t)b * 500 + (size_t)nsel * 5 + i] = 0.0f;
}

// ---------------------------------------------------------------- launch
extern "C" void kernel_launch(void* const* d_in, const int* in_sizes, int n_in,
                              void* d_out, int out_size, void* d_ws, size_t ws_size,
                              hipStream_t stream) {
  const float* p2 = (const float*)d_in[0];
  const float* p3 = (const float*)d_in[1];
  const float* p4 = (const float*)d_in[2];
  const float* p5 = (const float*)d_in[3];
  float* out = (float*)d_out;

  unsigned char* w = (unsigned char*)d_ws;
  u32*   hist     = (u32*)w;                    // hist, then bin cursors (in place)
  u32*   counters = (u32*)(w + WS_COUNTERS);
  uint2* compact  = (uint2*)(w + WS_COMPACT);
  u32*   scores   = (u32*)(w + WS_SCORES);

  zero_kernel<<<130, 1024, 0, stream>>>(hist);
  decode_score_hist<<<dim3(30, 32), 256, 0, stream>>>(p2, p3, p4, p5, scores, hist);
  scan_kernel<<<32, 256, 0, stream>>>(hist, counters);
  filter_kernel<<<dim3(15, 32), 256, 0, stream>>>(scores, hist, counters, compact);
  sort_nms_kernel<<<32, 1024, 0, stream>>>(compact, counters, p2, p3, p4, p5, out);
}

// Round 4
// 184.629 us; speedup vs baseline: 1.0276x; 1.0276x over previous
//
#include <hip/hip_runtime.h>
#include <cstdint>
#include <cstddef>

typedef unsigned int u32;
typedef unsigned long long u64;

#define NTOT 122740      // total proposals per batch
#define NQ   30685       // NTOT/4 uint4 per batch
#define NPAIR 61370      // NTOT/2 proposal pairs per batch
#define KTOP 1024        // top-K kept per batch (deterministic bin-cutoff set)
#define WIN  256         // IoU-matrix window over the sorted list
#define NBIN 4096
#define SCORE_T 0.25f
#define TBITS 0x3E800000u   // bit pattern of 0.25f

// level layout: [offset, count) per pyramid level (batch strides in floats: N*6)
// L2: [0,      92416)  152x152 s4   N=92416
// L3: [92416,  115520) 76x76   s8   N=23104
// L4: [115520, 121296) 38x38   s16  N=5776
// L5: [121296, 122740) 19x19   s32  N=1444

// ws layout (bytes):
//   hist:   32*4096*4 = 524288   @ 0
//   scores: 32*NTOT*4 = 15710720 @ 524288
#define WS_SCORES 524288

// ---------------------------------------------------------------- helpers
__device__ __forceinline__ float sigm(float x) { return 1.0f / (1.0f + expf(-x)); }

// valid scores [0.25,1) -> bins 1..4095 (monotone in bits); 0 = invalid
__device__ __forceinline__ int score_bin(u32 bits) {
  return min(4095, 1 + (int)((bits - TBITS) >> 12));
}

__device__ __forceinline__ u64 shfl_u64(u64 x, int src) {
  int lo = __shfl((int)(u32)x, src, 64);
  int hi = __shfl((int)(u32)(x >> 32), src, 64);
  return ((u64)(u32)hi << 32) | (u32)lo;
}

__device__ float4 decode_box_from_gidx(u32 gidx, int b,
    const float* __restrict__ p2, const float* __restrict__ p3,
    const float* __restrict__ p4, const float* __restrict__ p5)
{
  const float* p; int t, H, W; float stride;
  float aw0, ah0, aw1, ah1, aw2, ah2, aw3, ah3;
  if (gidx < 92416u) {
    p = p2 + (size_t)b * 92416 * 6; t = (int)gidx; H = 152; W = 152; stride = 4.0f;
    aw0=12.f; ah0=16.f; aw1=19.f; ah1=36.f; aw2=40.f; ah2=28.f; aw3=36.f; ah3=75.f;
  } else if (gidx < 115520u) {
    p = p3 + (size_t)b * 23104 * 6; t = (int)(gidx - 92416u); H = 76; W = 76; stride = 8.0f;
    aw0=36.f; ah0=75.f; aw1=76.f; ah1=55.f; aw2=72.f; ah2=146.f; aw3=142.f; ah3=110.f;
  } else if (gidx < 121296u) {
    p = p4 + (size_t)b * 5776 * 6; t = (int)(gidx - 115520u); H = 38; W = 38; stride = 16.0f;
    aw0=72.f; ah0=146.f; aw1=142.f; ah1=110.f; aw2=192.f; ah2=243.f; aw3=459.f; ah3=401.f;
  } else {
    p = p5 + (size_t)b * 1444 * 6; t = (int)(gidx - 121296u); H = 19; W = 19; stride = 32.0f;
    aw0=142.f; ah0=110.f; aw1=192.f; ah1=243.f; aw2=300.f; ah2=300.f; aw3=459.f; ah3=401.f;
  }
  int HW = H * W;
  int a = t / HW;
  int r = t - a * HW;
  int y = r / W;
  int x = r - y * W;
  const float* q = p + (size_t)t * 6;
  float2 t01 = *(const float2*)(q + 0);
  float2 t23 = *(const float2*)(q + 2);
  float cx = (sigm(t01.x) + (float)x) * stride;
  float cy = (sigm(t01.y) + (float)y) * stride;
  float aw = (a == 0) ? aw0 : (a == 1) ? aw1 : (a == 2) ? aw2 : aw3;
  float ah = (a == 0) ? ah0 : (a == 1) ? ah1 : (a == 2) ? ah2 : ah3;
  float bw = expf(t23.x) * aw;
  float bh = expf(t23.y) * ah;
  return make_float4(cx - 0.5f * bw, cy - 0.5f * bh, cx + 0.5f * bw, cy + 0.5f * bh);
}

__device__ __forceinline__ bool iou_gt(float4 A, float4 B) {
  float ltx = fmaxf(A.x, B.x), lty = fmaxf(A.y, B.y);
  float rbx = fminf(A.z, B.z), rby = fminf(A.w, B.w);
  float w = fmaxf(rbx - ltx, 0.0f), h = fmaxf(rby - lty, 0.0f);
  float inter = w * h;
  float a1 = fmaxf(A.z - A.x, 0.0f) * fmaxf(A.w - A.y, 0.0f);
  float a2 = fmaxf(B.z - B.x, 0.0f) * fmaxf(B.w - B.y, 0.0f);
  float iou = inter / (a1 + a2 - inter + 1e-9f);
  return iou > 0.5f;
}

// ---------------------------------------------------------------- A: decode scores + hist
__global__ __launch_bounds__(256)
void decode_score_hist(const float* __restrict__ p2, const float* __restrict__ p3,
                       const float* __restrict__ p4, const float* __restrict__ p5,
                       u32* __restrict__ scores, u32* __restrict__ hist)
{
  __shared__ u32 lhist[NBIN];
  const int tid = threadIdx.x;
  const int b = blockIdx.y;
  for (int i = tid; i < NBIN; i += 256) lhist[i] = 0u;
  __syncthreads();

  uint2* srow = (uint2*)(scores + (size_t)b * NTOT);
  const int pbase = blockIdx.x * 2048;
  #pragma unroll 2
  for (int k = 0; k < 8; ++k) {
    int P = pbase + k * 256 + tid;
    if (P < NPAIR) {
      int t0 = 2 * P;
      const float* p; int l0, LN;
      if (t0 < 92416)       { p = p2; l0 = t0;          LN = 92416; }
      else if (t0 < 115520) { p = p3; l0 = t0 - 92416;  LN = 23104; }
      else if (t0 < 121296) { p = p4; l0 = t0 - 115520; LN = 5776;  }
      else                  { p = p5; l0 = t0 - 121296; LN = 1444;  }
      const float* q = p + ((size_t)b * LN + (size_t)l0) * 6 + 4;
      float4 v1 = *(const float4*)(q);      // conf0, cls0, t0_1, t1_1
      float4 v2 = *(const float4*)(q + 4);  // t2_1, t3_1, conf1, cls1
      float s0 = sigm(v1.x) * sigm(v1.y);
      float s1 = sigm(v2.z) * sigm(v2.w);
      u32 b0 = (s0 >= SCORE_T) ? __float_as_uint(s0) : 0u;
      u32 b1 = (s1 >= SCORE_T) ? __float_as_uint(s1) : 0u;
      srow[P] = make_uint2(b0, b1);
      if (b0) atomicAdd(&lhist[score_bin(b0)], 1u);
      if (b1) atomicAdd(&lhist[score_bin(b1)], 1u);
    }
  }
  __syncthreads();
  u32* gh = hist + (size_t)b * NBIN;
  for (int i = tid; i < NBIN; i += 256) {
    u32 v = lhist[i];
    if (v) atomicAdd(&gh[i], v);
  }
}

// ---------------------------------------------------------------- M: fused scan+filter+sort+NMS
// One block per batch. Phases:
//  1. load hist row, suffix-scan in LDS -> cutoff B, n, per-bin start slots
//  2. scan scores slice (4-deep batched uint4), counting-scatter survivors into LDS
//  3. exact in-bin rank sort (barrier-free: slot = binstart + #greater bin-mates)
//  4. decode window boxes, IoU bitmask matrix (conflict-free mapping)
//  5. register-resident greedy NMS on wave 0, exact slow path, output
__global__ __launch_bounds__(1024, 1)
void mega_kernel(const u32* __restrict__ scores, const u32* __restrict__ hist,
                 const float* __restrict__ p2, const float* __restrict__ p3,
                 const float* __restrict__ p4, const float* __restrict__ p5,
                 float* __restrict__ out)
{
  const int b = blockIdx.x;
  const int tid = threadIdx.x;

  __shared__ u32 sstart[NBIN];      // 16 KB  bin start slot (immutable after phase 1)
  __shared__ u32 scur[NBIN];        // 16 KB  raw hist, then atomic cursors
  __shared__ u32 sscan[256];        // 1 KB
  __shared__ u64 skey[KTOP];        // 8 KB   scattered (bin-ordered) keys
  __shared__ u64 skey2[KTOP];       // 8 KB   exactly sorted keys
  __shared__ float4 sbox[WIN];      // 4 KB
  __shared__ u64 smat[WIN * 4];     // 8 KB   [word][row]
  __shared__ float4 selbox[100];    // 1.6 KB
  __shared__ int s_misc[4];         // [2]=n_sel, [3]=need slow
  __shared__ int s_B, s_n;

  // ---- phase 1: hist -> suffix scan -> B, n, bin starts
  const u32* gh = hist + (size_t)b * NBIN;
  for (int i = tid; i < NBIN; i += 1024) scur[i] = gh[i];   // raw counts
  __syncthreads();

  u32 loc[16]; int base = 0;
  if (tid < 256) {
    base = tid * 16;
    u32 g = 0;
    #pragma unroll
    for (int k = 0; k < 16; ++k) { loc[k] = scur[base + k]; g += loc[k]; }
    sscan[tid] = g;
  }
  __syncthreads();
  for (int off = 1; off < 256; off <<= 1) {
    u32 v = 0;
    if (tid < 256) v = (tid + off < 256) ? sscan[tid + off] : 0u;
    __syncthreads();
    if (tid < 256) sscan[tid] += v;
    __syncthreads();
  }
  // sscan[t] = cnt_ge(16t). cutoff B = min{bin : cnt_ge(bin) <= KTOP}, n = cnt_ge(B)
  if (tid == 0 && sscan[0] <= (u32)KTOP) { s_B = 1; s_n = (int)sscan[0]; }
  if (tid < 256) {
    u32 nxt = (tid < 255) ? sscan[tid + 1] : 0u;
    if (sscan[tid] > (u32)KTOP && nxt <= (u32)KTOP) {
      u32 c = nxt; int Bv = base + 16; u32 nv = nxt;
      for (int k = 15; k >= 0; --k) {
        c += loc[k];
        if (c <= (u32)KTOP) { Bv = base + k; nv = c; } else break;
      }
      s_B = Bv; s_n = (int)nv;
    }
    // bin start slot = cnt_ge(bin+1)
    u32 s = nxt;
    for (int k = 15; k >= 0; --k) { sstart[base + k] = s; s += loc[k]; }
  }
  __syncthreads();
  const int B = max(s_B, 1);
  const int n = min(s_n, KTOP);

  // ---- init cursors + sentinels
  for (int i = tid; i < NBIN; i += 1024) scur[i] = sstart[i];
  skey[tid] = 0ull;
  skey2[tid] = 0ull;
  __syncthreads();

  // ---- phase 2: filter + counting-scatter into LDS (4-deep batched loads)
  {
    const uint4* sp = (const uint4*)(scores + (size_t)b * NTOT);
    #pragma unroll 1
    for (int kk = 0; kk < 8; ++kk) {
      int i0 = kk * 4096 + tid;
      uint4 v0, v1, v2, v3;
      bool g0 = (i0        < NQ), g1 = (i0 + 1024 < NQ);
      bool g2 = (i0 + 2048 < NQ), g3 = (i0 + 3072 < NQ);
      if (g0) v0 = sp[i0];
      if (g1) v1 = sp[i0 + 1024];
      if (g2) v2 = sp[i0 + 2048];
      if (g3) v3 = sp[i0 + 3072];
      #pragma unroll
      for (int q = 0; q < 4; ++q) {
        bool gq = (q == 0) ? g0 : (q == 1) ? g1 : (q == 2) ? g2 : g3;
        if (!gq) continue;
        uint4 v = (q == 0) ? v0 : (q == 1) ? v1 : (q == 2) ? v2 : v3;
        int ii = i0 + q * 1024;
        u32 c4[4] = { v.x, v.y, v.z, v.w };
        #pragma unroll
        for (int c = 0; c < 4; ++c) {
          u32 bits = c4[c];
          if (bits) {
            int bin = score_bin(bits);
            if (bin >= B) {
              u32 slot = atomicAdd(&scur[bin], 1u);   // < n <= KTOP by construction
              if (slot < (u32)KTOP)
                skey[slot] = ((u64)bits << 32) | (u32)(~(u32)(4 * ii + c));
            }
          }
        }
      }
    }
  }
  __syncthreads();

  // ---- phase 3: exact rank sort within bins (barrier-free, wave-uniform broadcasts)
  // final slot of item = sstart[bin] + |{bin-mates with strictly greater key}|
  // keys are distinct (idx minor) -> bijective, exact (score desc, idx asc)
  for (int s = tid; s < n; s += 1024) {
    u64 k = skey[s];
    int bin = score_bin((u32)(k >> 32));
    int st = (int)sstart[bin];
    int en = (int)scur[bin];
    u32 r = 0;
    for (int j = st; j < en; ++j) r += (skey[j] > k) ? 1u : 0u;
    skey2[st + r] = k;
  }
  __syncthreads();

  const int Wn = min(n, WIN);

  // ---- phase 4a: decode boxes for the window
  if (tid < WIN) {
    sbox[tid] = (tid < Wn) ? decode_box_from_gidx(~(u32)skey2[tid], b, p2, p3, p4, p5)
                           : make_float4(0.f, 0.f, 0.f, 0.f);
  }
  __syncthreads();

  // ---- phase 4b: IoU bitmask matrix; row = tid&255, word = tid>>8 (broadcast reads)
  {
    int row = tid & 255, word = tid >> 8;
    u64 bits = 0;
    if (row < Wn) {
      float4 A = sbox[row];
      int j0 = word * 64;
      int je = min(64, Wn - j0);
      for (int j = 0; j < je; ++j)
        if (iou_gt(A, sbox[j0 + j])) bits |= (1ull << j);
    }
    smat[word * 256 + row] = bits;
  }
  __syncthreads();

  // ---- phase 5: greedy selection on wave 0, matrix rows in registers
  if (tid < 64) {
    const int lane = tid;
    u64 m0[4], m1[4], m2[4], m3[4];
    #pragma unroll
    for (int w = 0; w < 4; ++w) {
      m0[w] = smat[w * 256 +   0 + lane];
      m1[w] = smat[w * 256 +  64 + lane];
      m2[w] = smat[w * 256 + 128 + lane];
      m3[w] = smat[w * 256 + 192 + lane];
    }
    u64 live[4];
    #pragma unroll
    for (int g2 = 0; g2 < 4; ++g2) {
      int lo = g2 * 64;
      live[g2] = (Wn >= lo + 64) ? ~0ull : (Wn > lo ? ((1ull << (Wn - lo)) - 1ull) : 0ull);
    }
    int sel = 0;
    #pragma unroll 1
    for (int w2 = 0; w2 < 4; ++w2) {
      while (live[w2] && sel < 100) {
        int j = (int)__ffsll(live[w2]) - 1;
        int p = (w2 << 6) + j;
        u64 r0, r1, r2, r3;
        if (w2 == 0)      { r0 = shfl_u64(m0[0], j); r1 = shfl_u64(m0[1], j); r2 = shfl_u64(m0[2], j); r3 = shfl_u64(m0[3], j); }
        else if (w2 == 1) { r0 = shfl_u64(m1[0], j); r1 = shfl_u64(m1[1], j); r2 = shfl_u64(m1[2], j); r3 = shfl_u64(m1[3], j); }
        else if (w2 == 2) { r0 = shfl_u64(m2[0], j); r1 = shfl_u64(m2[1], j); r2 = shfl_u64(m2[2], j); r3 = shfl_u64(m2[3], j); }
        else              { r0 = shfl_u64(m3[0], j); r1 = shfl_u64(m3[1], j); r2 = shfl_u64(m3[2], j); r3 = shfl_u64(m3[3], j); }
        live[0] &= ~r0; live[1] &= ~r1; live[2] &= ~r2; live[3] &= ~r3;
        live[w2] &= ~(1ull << j);     // self-bit (IoU(self)=1 sets it anyway)
        if (lane == 0) {
          float4 box = sbox[p];
          u64 k = skey2[p];
          float sc = __uint_as_float((u32)(k >> 32));
          selbox[sel] = box;
          float* orow = out + (size_t)b * 500 + (size_t)sel * 5;
          orow[0] = box.x; orow[1] = box.y; orow[2] = box.z; orow[3] = box.w; orow[4] = sc;
        }
        sel++;
      }
    }
    if (lane == 0) {
      s_misc[2] = sel;
      s_misc[3] = (sel < 100 && n > WIN) ? 1 : 0;
    }
  }
  __syncthreads();

  // ---- exact slow path beyond the window (statistically never taken)
  if (s_misc[3]) {
    if (tid < 64) {
      const int lane = tid;
      int sel = s_misc[2];
      for (int p = WIN; p < n && sel < 100; ++p) {
        u64 k = skey2[p];
        float4 box = decode_box_from_gidx(~(u32)k, b, p2, p3, p4, p5);
        bool hit = false;
        if (lane < sel) hit = iou_gt(selbox[lane], box);
        if (lane + 64 < sel) hit = hit || iou_gt(selbox[lane + 64], box);
        u64 anyhit = __ballot(hit);
        if (anyhit == 0ull) {
          if (lane == 0) {
            selbox[sel] = box;
            float sc = __uint_as_float((u32)(k >> 32));
            float* orow = out + (size_t)b * 500 + (size_t)sel * 5;
            orow[0] = box.x; orow[1] = box.y; orow[2] = box.z; orow[3] = box.w; orow[4] = sc;
          }
          sel++;
        }
      }
      if (lane == 0) s_misc[2] = sel;
    }
  }
  __syncthreads();

  // ---- zero-fill remaining rows
  const int nsel = s_misc[2];
  for (int i = tid; i < (100 - nsel) * 5; i += 1024)
    out[(size_t)b * 500 + (size_t)nsel * 5 + i] = 0.0f;
}

// ---------------------------------------------------------------- launch
extern "C" void kernel_launch(void* const* d_in, const int* in_sizes, int n_in,
                              void* d_out, int out_size, void* d_ws, size_t ws_size,
                              hipStream_t stream) {
  const float* p2 = (const float*)d_in[0];
  const float* p3 = (const float*)d_in[1];
  const float* p4 = (const float*)d_in[2];
  const float* p5 = (const float*)d_in[3];
  float* out = (float*)d_out;

  unsigned char* w = (unsigned char*)d_ws;
  u32* hist   = (u32*)w;
  u32* scores = (u32*)(w + WS_SCORES);

  hipMemsetAsync(hist, 0, 32 * NBIN * sizeof(u32), stream);
  decode_score_hist<<<dim3(30, 32), 256, 0, stream>>>(p2, p3, p4, p5, scores, hist);
  mega_kernel<<<32, 1024, 0, stream>>>(scores, hist, p2, p3, p4, p5, out);
}